// Round 5
// baseline (333.578 us; speedup 1.0000x reference)
//
#include <hip/hip_runtime.h>
#include <math.h>

#define NL 8
#define NP 512
#define NC 64
#define NF 128
#define NALL 192
#define NRAY (NL * NP)
#define HID 128

typedef _Float16 half8 __attribute__((ext_vector_type(8)));
typedef _Float16 half4v __attribute__((ext_vector_type(4)));
typedef float floatx16 __attribute__((ext_vector_type(16)));

#define MFMA(a, b, c) __builtin_amdgcn_mfma_f32_32x32x16_f16((a), (b), (c), 0, 0, 0)

__device__ __forceinline__ float dcoarse_at(int i) {
    float t = (float)i * 0.015625f; // i/64, exact in fp32
    return 1e-3f * (1.0f - t) + 0.5f * t;
}

__device__ __forceinline__ floatx16 fzero16() {
    floatx16 z;
#pragma unroll
    for (int i = 0; i < 16; ++i) z[i] = 0.f;
    return z;
}
__device__ __forceinline__ half8 hzero8() {
    half8 z;
#pragma unroll
    for (int i = 0; i < 8; ++i) z[i] = (_Float16)0.f;
    return z;
}

// Wsp layout (per layer L in {0:w1, 1:w2}, plane p in {hi,lo}):
//   Wsp[(L*2+p)*16384 + f],  f = (((jt*8+ks)*2+lhi)*32 + l31)*8 + i
//   holding split(w[(ks*16+lhi*8+i)*128 + (jt*32+l31)]).
// One A-fragment (jt,ks) = 1 KB contiguous -> fully coalesced wave load.
__global__ void prep_kernel(const float* __restrict__ w1, const float* __restrict__ w2,
                            _Float16* __restrict__ Wsp) {
    int f = blockIdx.x * 256 + threadIdx.x;   // [0, 16384)
    int layer = blockIdx.y;
    const float* w = layer ? w2 : w1;
    int i = f & 7, l31 = (f >> 3) & 31, lhi = (f >> 8) & 1, ks = (f >> 9) & 7, jt = f >> 12;
    int j = jt * 32 + l31;
    int k = ks * 16 + lhi * 8 + i;
    float v = w[k * 128 + j];
    _Float16 hi = (_Float16)v;
    Wsp[(layer * 2 + 0) * 16384 + f] = hi;
    Wsp[(layer * 2 + 1) * 16384 + f] = (_Float16)(v - (float)hi);
}

// Fused 4-layer MLP over 128 points per block, split-fp16 MFMA.
// 4 waves; wave wv owns m-tile (32 points) x full j (4 j-tiles) -> 4 acc chains.
// H planes in LDS, 16B-chunk XOR swizzle (all 8 bank-groups hit uniformly).
// B (activations) layer-resident in regs; A (weights) streamed coalesced from Wsp
// (all 4 waves stream identical addresses -> L1 temporal reuse).
template<int MODE, int FASTW>   // MODE 0: coarse (d computed), 1: fine (d from d_all)
__global__ __launch_bounds__(256, 2) void mlp_kernel(
    const float* __restrict__ pts, const float* __restrict__ lights,
    const float* __restrict__ d_all,
    const float* __restrict__ w0, const float* __restrict__ b0,
    const float* __restrict__ w1, const float* __restrict__ b1,
    const float* __restrict__ w2, const float* __restrict__ b2,
    const float* __restrict__ w3, const float* __restrict__ b3,
    const _Float16* __restrict__ Wsp,
    float* __restrict__ sdf_out)
{
    __shared__ __align__(16) _Float16 Hhi[128 * 128];
    __shared__ __align__(16) _Float16 Hlo[128 * 128];
    __shared__ _Float16 Xs[6 * 128];   // hi c0,c1,c2 then lo c0,c1,c2

    const int tid = threadIdx.x;
    const int lane = tid & 63;
    const int wv = tid >> 6;                 // m-tile index
    const int l31 = lane & 31, lhi = lane >> 5;
    const int base = blockIdx.x * 128;
    const int m = wv * 32 + l31;             // this lane's point (MFMA C column)
    const int msw = m & 15;

    // swizzled H address (halves) for element (m, k): chunk = k>>3 XOR (m&15)
    auto haddr = [&](int k0) { return m * 128 + ((((k0 >> 3) ^ msw) << 3) | (k0 & 7)); };

    // ---- phase A: per-point coords, split to fp16 hi/lo in LDS
    if (tid < 128) {
        int pt = base + tid;
        int ray; float d;
        if (MODE == 0) { ray = pt >> 6; d = dcoarse_at(pt & 63); }
        else           { ray = (int)((unsigned)pt / 192u); d = d_all[pt]; }
        int l = ray >> 9, p = ray & (NP - 1);
        float px = pts[p * 3 + 0], py = pts[p * 3 + 1], pz = pts[p * 3 + 2];
        float dx = lights[l * 3 + 0] - px, dy = lights[l * 3 + 1] - py, dz = lights[l * 3 + 2] - pz;
        float n = sqrtf(dx * dx + dy * dy + dz * dz);
        dx /= n; dy /= n; dz /= n;
        float xc[3] = { px + d * dx, py + d * dy, pz + d * dz };
#pragma unroll
        for (int c = 0; c < 3; ++c) {
            _Float16 h = (_Float16)xc[c];
            Xs[c * 128 + tid] = h;
            Xs[(3 + c) * 128 + tid] = (_Float16)(xc[c] - (float)h);
        }
    }
    __syncthreads();

    // epilogue helper: bias+relu+split, write C tile (this lane's column m, j-tile jt)
    auto store_tile = [&](const floatx16& a, int jt, const float* __restrict__ bias) {
#pragma unroll
        for (int g = 0; g < 4; ++g) {
            int jg = jt * 32 + 8 * g + 4 * lhi;
            half4v hq, lq;
#pragma unroll
            for (int q = 0; q < 4; ++q) {
                float v = fmaxf(a[g * 4 + q] + bias[jg + q], 0.f);
                _Float16 hi = (_Float16)v;
                hq[q] = hi;
                lq[q] = (_Float16)(v - (float)hi);
            }
            int ad = haddr(jg);
            *(half4v*)&Hhi[ad] = hq;
            *(half4v*)&Hlo[ad] = lq;
        }
    };

    floatx16 acc[4];

    // ---- Layer 1: 3->128 as one K=16 MFMA step (k>=3 zero-padded)
    {
        half8 a1h[4], a1l[4], bh1, bl1;
#pragma unroll
        for (int jt = 0; jt < 4; ++jt) { a1h[jt] = hzero8(); a1l[jt] = hzero8(); }
        bh1 = hzero8(); bl1 = hzero8();
        if (lhi == 0) {
#pragma unroll
            for (int jt = 0; jt < 4; ++jt) {
                int j = jt * 32 + l31;
#pragma unroll
                for (int c = 0; c < 3; ++c) {
                    float v = w0[c * 128 + j];
                    _Float16 hi = (_Float16)v;
                    a1h[jt][c] = hi;
                    a1l[jt][c] = (_Float16)(v - (float)hi);
                }
            }
#pragma unroll
            for (int c = 0; c < 3; ++c) { bh1[c] = Xs[c * 128 + m]; bl1[c] = Xs[(3 + c) * 128 + m]; }
        }
#pragma unroll
        for (int jt = 0; jt < 4; ++jt) acc[jt] = fzero16();
#pragma unroll
        for (int jt = 0; jt < 4; ++jt) acc[jt] = MFMA(a1l[jt], bh1, acc[jt]);
#pragma unroll
        for (int jt = 0; jt < 4; ++jt) acc[jt] = MFMA(a1h[jt], bl1, acc[jt]);
#pragma unroll
        for (int jt = 0; jt < 4; ++jt) acc[jt] = MFMA(a1h[jt], bh1, acc[jt]);
#pragma unroll
        for (int jt = 0; jt < 4; ++jt) store_tile(acc[jt], jt, b0);
    }
    __syncthreads();   // H1 visible to all waves

    // layer core: read this wave's B (16 x b128), barrier, then 96 MFMAs streaming A
    auto gemm_layer = [&](int L, const float* __restrict__ wfull) {
        half8 bh[8], bl[8];
#pragma unroll
        for (int ks = 0; ks < 8; ++ks) {
            int ad = haddr(ks * 16 + lhi * 8);
            bh[ks] = *(const half8*)&Hhi[ad];
            bl[ks] = *(const half8*)&Hlo[ad];
        }
        __syncthreads();   // all B reads done -> in-place H overwrite is safe later
#pragma unroll
        for (int jt = 0; jt < 4; ++jt) acc[jt] = fzero16();
#pragma unroll
        for (int ks = 0; ks < 8; ++ks) {
            half8 ah[4], al[4];
#pragma unroll
            for (int jt = 0; jt < 4; ++jt) {
                if (FASTW) {
                    int off = (((jt * 8 + ks) * 2 + lhi) * 32 + l31) * 8;
                    ah[jt] = *(const half8*)&Wsp[(L * 2 + 0) * 16384 + off];
                    al[jt] = *(const half8*)&Wsp[(L * 2 + 1) * 16384 + off];
                } else {
                    int j = jt * 32 + l31, k0 = ks * 16 + lhi * 8;
#pragma unroll
                    for (int i = 0; i < 8; ++i) {
                        float v = wfull[(k0 + i) * 128 + j];
                        _Float16 hi = (_Float16)v;
                        ah[jt][i] = hi;
                        al[jt][i] = (_Float16)(v - (float)hi);
                    }
                }
            }
#pragma unroll
            for (int jt = 0; jt < 4; ++jt) acc[jt] = MFMA(al[jt], bh[ks], acc[jt]);
#pragma unroll
            for (int jt = 0; jt < 4; ++jt) acc[jt] = MFMA(ah[jt], bl[ks], acc[jt]);
#pragma unroll
            for (int jt = 0; jt < 4; ++jt) acc[jt] = MFMA(ah[jt], bh[ks], acc[jt]);
        }
    };

    // ---- Layer 2: H1 -> H2 (in place)
    gemm_layer(0, w1);
#pragma unroll
    for (int jt = 0; jt < 4; ++jt) store_tile(acc[jt], jt, b1);
    __syncthreads();   // H2 visible

    // ---- Layer 3 (+ Layer 4 reduce in regs, no write-back)
    gemm_layer(1, w2);
    float p = 0.f;
#pragma unroll
    for (int jt = 0; jt < 4; ++jt)
#pragma unroll
        for (int g = 0; g < 4; ++g) {
            int jg = jt * 32 + 8 * g + 4 * lhi;
#pragma unroll
            for (int q = 0; q < 4; ++q) {
                float v = fmaxf(acc[jt][g * 4 + q] + b2[jg + q], 0.f);
                p = fmaf(v, w3[jg + q], p);
            }
        }
    p += __shfl_xor(p, 32);
    if (lane < 32) sdf_out[base + m] = b3[0] + p;
}

// One wave per ray, barrier-free: shfl scans for cdf, shfl binary-search for
// sample_pdf (exact searchsorted-count semantics on strictly-increasing cdf),
// then 256-item bitonic sort on 64 lanes x 4 registers (padded with +inf).
__global__ __launch_bounds__(256) void sample_kernel(
    const float* __restrict__ sdf_c, const float* __restrict__ u,
    float* __restrict__ d_all) {
    const int lane = threadIdx.x & 63, wv = threadIdx.x >> 6;
    const int ray = blockIdx.x * 4 + wv;

    // ---- cdf (same math as block version: sigmoid->alpha->T->w->cdf)
    float sv = sdf_c[ray * NC + lane];
    float c = 1.0f / (1.0f + expf(-100.0f * sv));
    float cn = __shfl_down(c, 1);
    bool valid = lane < 63;
    float a = valid ? fmaxf((c - cn) / (c + 1e-10f), 0.f) : 0.f;
    float sh = valid ? (1.f - a + 1e-10f) : 1.f;
    float ps = sh;
#pragma unroll
    for (int off = 1; off < 64; off <<= 1) { float o = __shfl_up(ps, off); if (lane >= off) ps *= o; }
    float T = __shfl_up(ps, 1);
    if (lane == 0) T = 1.f;
    float w = valid ? (a * T + 1e-5f) : 0.f;
    float wsum = w;
#pragma unroll
    for (int off = 1; off < 64; off <<= 1) wsum += __shfl_xor(wsum, off);
    float pdf = w / wsum;
    float cs = pdf;
#pragma unroll
    for (int off = 1; off < 64; off <<= 1) { float o = __shfl_up(cs, off); if (lane >= off) cs += o; }
    float cdfv = __shfl_up(cs, 1);
    if (lane == 0) cdfv = 0.f;    // cdfv = cdf[lane], strictly increasing, cdf[0]=0

    // ---- fine samples: 2 u's per lane -> sort items t=1,2
    float v[4];
    v[0] = dcoarse_at(lane);
    v[3] = __builtin_inff();
#pragma unroll
    for (int t = 0; t < 2; ++t) {
        float uu = u[ray * NF + t * 64 + lane];
        int lo = 0;
#pragma unroll
        for (int b = 32; b >= 1; b >>= 1) {
            float cm = __shfl(cdfv, lo + b);
            if (uu >= cm) lo += b;
        }
        int above = min(lo + 1, NC - 1);
        float cb = __shfl(cdfv, lo), ca = __shfl(cdfv, above);
        float bb = dcoarse_at(lo), ba = dcoarse_at(above);
        float denom = ca - cb;
        if (denom < 1e-5f) denom = 1.f;
        float tt = (uu - cb) / denom;
        v[1 + t] = bb + tt * (ba - bb);
    }

    // ---- bitonic sort, item index i = t*64 + lane
    for (int k = 2; k <= 256; k <<= 1) {
        for (int j = k >> 1; j > 0; j >>= 1) {
            if (j >= 64) {
                int tj = j >> 6;
#pragma unroll
                for (int t = 0; t < 4; ++t) {
                    if ((t & tj) == 0) {
                        int t2 = t ^ tj;
                        bool asc = (((t * 64) & k) == 0);
                        float x = v[t], y = v[t2];
                        bool sw = asc ? (x > y) : (x < y);
                        if (sw) { v[t] = y; v[t2] = x; }
                    }
                }
            } else {
#pragma unroll
                for (int t = 0; t < 4; ++t) {
                    int i = t * 64 + lane;
                    float other = __shfl_xor(v[t], j);
                    bool lower = (lane & j) == 0;
                    bool asc = ((i & k) == 0);
                    v[t] = (lower == asc) ? fminf(v[t], other) : fmaxf(v[t], other);
                }
            }
        }
    }
#pragma unroll
    for (int t = 0; t < 3; ++t) d_all[ray * NALL + t * 64 + lane] = v[t];
}

// One wave per ray: chunked (3/lane) product scan for T, occu sum, out = 1-occu.
__global__ __launch_bounds__(256) void finish_kernel(
    const float* __restrict__ sdf_a, float* __restrict__ out) {
    int lane = threadIdx.x & 63, wv = threadIdx.x >> 6;
    int ray = blockIdx.x * 4 + wv;
    const float* S = sdf_a + (size_t)ray * NALL;
    float c[4];
#pragma unroll
    for (int t = 0; t < 4; ++t) {
        int i = lane * 3 + t;
        c[t] = (i < NALL) ? 1.0f / (1.0f + expf(-100.0f * S[i])) : 0.f;
    }
    float a[3], s[3];
#pragma unroll
    for (int t = 0; t < 3; ++t) {
        int i = lane * 3 + t;
        if (i < NALL - 1) {
            a[t] = fmaxf((c[t] - c[t + 1]) / (c[t] + 1e-10f), 0.f);
            s[t] = 1.f - a[t] + 1e-10f;
        } else { a[t] = 0.f; s[t] = 1.f; }
    }
    float chunk = s[0] * s[1] * s[2];
    float ps = chunk;
#pragma unroll
    for (int off = 1; off < 64; off <<= 1) {
        float o = __shfl_up(ps, off);
        if (lane >= off) ps *= o;
    }
    float T = __shfl_up(ps, 1);
    if (lane == 0) T = 1.f;
    float occ = a[0] * T;
    T *= s[0]; occ = fmaf(a[1], T, occ);
    T *= s[1]; occ = fmaf(a[2], T, occ);
#pragma unroll
    for (int off = 1; off < 64; off <<= 1) occ += __shfl_xor(occ, off);
    if (lane == 0) out[ray] = 1.f - occ;
}

extern "C" void kernel_launch(void* const* d_in, const int* in_sizes, int n_in,
                              void* d_out, int out_size, void* d_ws, size_t ws_size,
                              hipStream_t stream) {
    const float* pts = (const float*)d_in[0];
    const float* lights = (const float*)d_in[1];
    const float* u = (const float*)d_in[2];
    const float* w0 = (const float*)d_in[3];
    const float* b0 = (const float*)d_in[4];
    const float* w1 = (const float*)d_in[5];
    const float* b1 = (const float*)d_in[6];
    const float* w2 = (const float*)d_in[7];
    const float* b2 = (const float*)d_in[8];
    const float* w3 = (const float*)d_in[9];
    const float* b3 = (const float*)d_in[10];
    float* out = (float*)d_out;

    float* ws = (float*)d_ws;
    float* d_all = ws;                          // NRAY*NALL
    float* sdf = ws + (size_t)NRAY * NALL;      // NRAY*NALL (coarse uses first NRAY*NC)

    const size_t base_bytes = (size_t)2 * NRAY * NALL * 4;
    const bool fast = ws_size >= base_bytes + 4 * 16384 * sizeof(_Float16);
    _Float16* Wsp = (_Float16*)((char*)d_ws + base_bytes);

    if (fast) {
        prep_kernel<<<dim3(64, 2), 256, 0, stream>>>(w1, w2, Wsp);
        mlp_kernel<0, 1><<<(NRAY * NC) / 128, 256, 0, stream>>>(
            pts, lights, nullptr, w0, b0, w1, b1, w2, b2, w3, b3, Wsp, sdf);
        sample_kernel<<<NRAY / 4, 256, 0, stream>>>(sdf, u, d_all);
        mlp_kernel<1, 1><<<(NRAY * NALL) / 128, 256, 0, stream>>>(
            pts, lights, d_all, w0, b0, w1, b1, w2, b2, w3, b3, Wsp, sdf);
    } else {
        mlp_kernel<0, 0><<<(NRAY * NC) / 128, 256, 0, stream>>>(
            pts, lights, nullptr, w0, b0, w1, b1, w2, b2, w3, b3, nullptr, sdf);
        sample_kernel<<<NRAY / 4, 256, 0, stream>>>(sdf, u, d_all);
        mlp_kernel<1, 0><<<(NRAY * NALL) / 128, 256, 0, stream>>>(
            pts, lights, d_all, w0, b0, w1, b1, w2, b2, w3, b3, nullptr, sdf);
    }
    finish_kernel<<<NRAY / 4, 256, 0, stream>>>(sdf, out);
}